// Round 6
// baseline (1034.572 us; speedup 1.0000x reference)
//
#include <hip/hip_runtime.h>

#define S_LEN 2048
#define DMODEL 1024
#define NH 16
#define DK 64
#define BATCH 2
#define BS (BATCH * S_LEN)  // 4096
#define KHALF 1024

typedef _Float16 f16;
typedef _Float16 f16x8 __attribute__((ext_vector_type(8)));
typedef _Float16 f16x4 __attribute__((ext_vector_type(4)));
typedef float f32x4 __attribute__((ext_vector_type(4)));

__device__ __forceinline__ f32x4 mfma16(f16x8 a, f16x8 b, f32x4 c) {
  return __builtin_amdgcn_mfma_f32_16x16x32_f16(a, b, c, 0, 0, 0);
}

// ---------------------------------------------------------------------------
// Pre-convert fp32 -> f16 for all GEMM operands (activations + weights).
// ---------------------------------------------------------------------------
__global__ __launch_bounds__(256) void cvt6(
    const float* __restrict__ a0, const float* __restrict__ a1,
    const float* __restrict__ a2, const float* __restrict__ a3,
    const float* __restrict__ a4, const float* __restrict__ a5,
    f16* __restrict__ d0, f16* __restrict__ d1, f16* __restrict__ d2,
    f16* __restrict__ d3, f16* __restrict__ d4, f16* __restrict__ d5) {
  const int y = blockIdx.y;
  const float* s;
  f16* d;
  switch (y) {
    case 0: s = a0; d = d0; break;
    case 1: s = a1; d = d1; break;
    case 2: s = a2; d = d2; break;
    case 3: s = a3; d = d3; break;
    case 4: s = a4; d = d4; break;
    default: s = a5; d = d5; break;
  }
  const int n = (y < 3) ? BS * DMODEL : DMODEL * DMODEL;
  const int idx = (blockIdx.x * 256 + threadIdx.x) * 4;
  if (idx >= n) return;
  const float4 v = *reinterpret_cast<const float4*>(&s[idx]);
  f16x4 h = {(f16)v.x, (f16)v.y, (f16)v.z, (f16)v.w};
  *reinterpret_cast<f16x4*>(&d[idx]) = h;
}

// ---------------------------------------------------------------------------
// All-f16 NT GEMM, BK=64.
// MODE 0: f16 head-split [B][H][S][DK]; MODE 1: f16 [B][H][DK][S];
// MODE 2: fp32 row-major.
// ---------------------------------------------------------------------------
template <int MODE>
__device__ __forceinline__ void gemm_body16(const f16* __restrict__ A,
                                            const f16* __restrict__ W,
                                            const float* __restrict__ bias,
                                            void* __restrict__ outp, float scale,
                                            f16 (*As)[72], f16 (*Ws)[72]) {
  const int t = threadIdx.x;
  const int m0 = blockIdx.y * 128;
  const int n0 = blockIdx.x * 128;
  const int wave = t >> 6, lane = t & 63;
  const int wr = wave >> 1, wc = wave & 1;
  const int lcol = lane & 15, kq = lane >> 4;

  f32x4 acc[4][4];
  const f32x4 zero = {0.f, 0.f, 0.f, 0.f};
#pragma unroll
  for (int i = 0; i < 4; ++i)
#pragma unroll
    for (int j = 0; j < 4; ++j) acc[i][j] = zero;

  for (int k0 = 0; k0 < DMODEL; k0 += 64) {
#pragma unroll
    for (int i = 0; i < 4; ++i) {
      const int f = t + i * 256;
      const int r = f >> 3, c = (f & 7) << 3;
      *reinterpret_cast<f16x8*>(&As[r][c]) =
          *reinterpret_cast<const f16x8*>(&A[(size_t)(m0 + r) * DMODEL + k0 + c]);
      *reinterpret_cast<f16x8*>(&Ws[r][c]) =
          *reinterpret_cast<const f16x8*>(&W[(size_t)(n0 + r) * DMODEL + k0 + c]);
    }
    __syncthreads();
#pragma unroll
    for (int ks = 0; ks < 2; ++ks) {
      f16x8 af[4], bf[4];
#pragma unroll
      for (int fr = 0; fr < 4; ++fr)
        af[fr] = *reinterpret_cast<const f16x8*>(
            &As[wr * 64 + fr * 16 + lcol][ks * 32 + kq * 8]);
#pragma unroll
      for (int fc = 0; fc < 4; ++fc)
        bf[fc] = *reinterpret_cast<const f16x8*>(
            &Ws[wc * 64 + fc * 16 + lcol][ks * 32 + kq * 8]);
#pragma unroll
      for (int fr = 0; fr < 4; ++fr)
#pragma unroll
        for (int fc = 0; fc < 4; ++fc)
          acc[fr][fc] = mfma16(af[fr], bf[fc], acc[fr][fc]);
    }
    __syncthreads();
  }

#pragma unroll
  for (int fc = 0; fc < 4; ++fc) {
    const int gj = n0 + wc * 64 + fc * 16 + lcol;
    const float bv = bias[gj];
#pragma unroll
    for (int fr = 0; fr < 4; ++fr) {
#pragma unroll
      for (int r = 0; r < 4; ++r) {
        const int gi = m0 + wr * 64 + fr * 16 + kq * 4 + r;
        const float val = (acc[fr][fc][r] + bv) * scale;
        if constexpr (MODE == 0) {
          const int b = gi >> 11, s = gi & 2047, h = gj >> 6, dk = gj & 63;
          ((f16*)outp)[(((size_t)(b * NH + h) * S_LEN) + s) * DK + dk] = (f16)val;
        } else if constexpr (MODE == 1) {
          const int b = gi >> 11, s = gi & 2047, h = gj >> 6, dk = gj & 63;
          ((f16*)outp)[(((size_t)(b * NH + h) * DK) + dk) * S_LEN + s] = (f16)val;
        } else {
          ((float*)outp)[(size_t)gi * DMODEL + gj] = val;
        }
      }
    }
  }
}

// Fused q/k/v projections (z selects). q output pre-scaled by 1/sqrt(DK).
__global__ __launch_bounds__(256, 3) void qkv_gemm(
    const f16* __restrict__ qf, const f16* __restrict__ kf,
    const f16* __restrict__ vf, const f16* __restrict__ wq,
    const float* __restrict__ b_q, const f16* __restrict__ wv,
    const float* __restrict__ b_v, f16* __restrict__ qh, f16* __restrict__ kh,
    f16* __restrict__ vhT) {
  __shared__ f16 As[128][72];
  __shared__ f16 Ws[128][72];
  if (blockIdx.z == 0)
    gemm_body16<0>(qf, wq, b_q, qh, 0.125f, As, Ws);
  else if (blockIdx.z == 1)
    gemm_body16<0>(kf, wq, b_q, kh, 1.0f, As, Ws);
  else
    gemm_body16<1>(vf, wv, b_v, vhT, 1.0f, As, Ws);
}

__global__ __launch_bounds__(256, 2) void gemm_out(const f16* __restrict__ A,
                                                   const f16* __restrict__ W,
                                                   const float* __restrict__ bias,
                                                   float* __restrict__ outp) {
  __shared__ f16 As[128][72];
  __shared__ f16 Ws[128][72];
  gemm_body16<2>(A, W, bias, outp, 1.0f, As, Ws);
}

// ---------------------------------------------------------------------------
// Fused attention, swapped-operand QK^T -> ZERO main-loop LDS traffic.
//   block = 4 waves over 64 Q-rows; wave = (row-half rh, K-half khf):
//   32 rows x 1024 cols per wave (rt=2 ILP, 16+ waves/CU TLP).
// QK: mfma(K_frag, Q_frag) -> lane holds P[k = jt*16+kq*4+r][q = lcol]:
//   the k-axis is lane-local in 4-groups. exp in-register.
// PV: A-frag = in-register repack of the lane's own 16 exp values under the
//   k-permutation pi(kq,e) = ks*32+(e>>2)*16+kq*4+(e&3); V loaded with the
//   same pi (two 8B loads) -> PV valid with NO shuffles and NO LDS.
//   Output C-layout identical to the old version (epilogue unchanged).
// attn stores: lane owns 4 consecutive k -> float4 stores.
// Sweep 1: l_partial + unnormalized O_partial. Cross-wave combine via LDS.
// Sweep 2: recompute own K-half, write attn = exp(s)*il fp32-exact.
// ---------------------------------------------------------------------------
__global__ __launch_bounds__(256, 4) void attn_fused(
    const f16* __restrict__ qh, const f16* __restrict__ kh,
    const f16* __restrict__ vhT, const int* __restrict__ mask,
    float* __restrict__ attn, f16* __restrict__ ctx) {
  // Ost f32 [64][68] (17408 B) + lred f32 [2][64] (512 B)
  __shared__ __align__(16) unsigned char smem[17920];
  const int t = threadIdx.x;
  const int bh = blockIdx.y, b = bh >> 4, h = bh & 15;
  const int i0 = blockIdx.x * 64;
  const int wave = t >> 6, lane = t & 63;
  const int rh = wave & 1, khf = wave >> 1;
  const int lcol = lane & 15, kq = lane >> 4;
  const int rbase = i0 + rh * 32;
  const int jbase = khf * KHALF;
  float (*Ost)[68] = reinterpret_cast<float(*)[68]>(smem);
  float* lred = reinterpret_cast<float*>(smem + 17408);  // [2][64]

  const f16* Q = qh + (size_t)bh * S_LEN * DK;
  const f16* K = kh + (size_t)bh * S_LEN * DK;
  const f16* V = vhT + (size_t)bh * DK * S_LEN;
  const int* msk = mask + b * S_LEN;
  float* Sc = attn + (size_t)bh * S_LEN * S_LEN;

  // Q fragments (B-operand of swapped QK; same addresses as before)
  f16x8 aq[2][2];
#pragma unroll
  for (int rt = 0; rt < 2; ++rt)
#pragma unroll
    for (int ks = 0; ks < 2; ++ks)
      aq[rt][ks] = *reinterpret_cast<const f16x8*>(
          &Q[(size_t)(rbase + rt * 16 + lcol) * DK + ks * 32 + kq * 8]);

  float l_acc[2] = {0.f, 0.f};
  f32x4 o[2][4];
  const f32x4 zero = {0.f, 0.f, 0.f, 0.f};
#pragma unroll
  for (int rt = 0; rt < 2; ++rt)
#pragma unroll
    for (int d = 0; d < 4; ++d) o[rt][d] = zero;

  // ---- sweep 1 (own K-half): l_partial + unnormalized PV, zero LDS ----
  for (int j0 = jbase; j0 < jbase + KHALF; j0 += 64) {
#pragma unroll
    for (int jh = 0; jh < 2; ++jh) {  // jh == ks (32-k chunk)
      f16x8 ap[2];
#pragma unroll
      for (int jl = 0; jl < 2; ++jl) {
        const int jt = jh * 2 + jl;
        const f16* Krow = &K[(size_t)(j0 + jt * 16 + lcol) * DK + kq * 8];
        const f16x8 bk0 = *reinterpret_cast<const f16x8*>(Krow);
        const f16x8 bk1 = *reinterpret_cast<const f16x8*>(Krow + 32);
        const int4 m4 =
            *reinterpret_cast<const int4*>(&msk[j0 + jt * 16 + kq * 4]);
#pragma unroll
        for (int rt = 0; rt < 2; ++rt) {
          f32x4 c = zero;
          c = mfma16(bk0, aq[rt][0], c);
          c = mfma16(bk1, aq[rt][1], c);
          const float p0 = m4.x ? __expf(c[0]) : 0.f;
          const float p1 = m4.y ? __expf(c[1]) : 0.f;
          const float p2 = m4.z ? __expf(c[2]) : 0.f;
          const float p3 = m4.w ? __expf(c[3]) : 0.f;
          l_acc[rt] += (p0 + p1) + (p2 + p3);
          ap[rt][jl * 4 + 0] = (f16)p0;
          ap[rt][jl * 4 + 1] = (f16)p1;
          ap[rt][jl * 4 + 2] = (f16)p2;
          ap[rt][jl * 4 + 3] = (f16)p3;
        }
      }
      // PV for this 32-k chunk: V loaded under the same pi (lane-local k)
#pragma unroll
      for (int d = 0; d < 4; ++d) {
        const f16* Vr =
            &V[(size_t)(d * 16 + lcol) * S_LEN + j0 + jh * 32 + kq * 4];
        const f16x4 v0 = *reinterpret_cast<const f16x4*>(Vr);
        const f16x4 v1 = *reinterpret_cast<const f16x4*>(Vr + 16);
        f16x8 bv;
        bv[0] = v0[0]; bv[1] = v0[1]; bv[2] = v0[2]; bv[3] = v0[3];
        bv[4] = v1[0]; bv[5] = v1[1]; bv[6] = v1[2]; bv[7] = v1[3];
#pragma unroll
        for (int rt = 0; rt < 2; ++rt) o[rt][d] = mfma16(ap[rt], bv, o[rt][d]);
      }
    }
  }

  // ---- reduce l over the 4 kq lane-groups (k-axis) ----
#pragma unroll
  for (int rt = 0; rt < 2; ++rt) {
    float es = l_acc[rt];
    es += __shfl_xor(es, 16);
    es += __shfl_xor(es, 32);
    l_acc[rt] = es;
  }

  // ---- cross-wave combine staging (first smem use; one barrier) ----
  if (kq == 0) {
#pragma unroll
    for (int rt = 0; rt < 2; ++rt)
      lred[khf * 64 + rh * 32 + rt * 16 + lcol] = l_acc[rt];
  }
  if (khf == 1) {
#pragma unroll
    for (int rt = 0; rt < 2; ++rt)
#pragma unroll
      for (int d = 0; d < 4; ++d)
#pragma unroll
        for (int r = 0; r < 4; ++r)
          Ost[rh * 32 + rt * 16 + kq * 4 + r][d * 16 + lcol] = o[rt][d][r];
  }
  __syncthreads();

  float ile[2][4];  // q = kq*4+r layout (epilogue)
  float il2[2];     // q = lcol layout (sweep 2 stores)
#pragma unroll
  for (int rt = 0; rt < 2; ++rt) {
#pragma unroll
    for (int r = 0; r < 4; ++r) {
      const int rl = rh * 32 + rt * 16 + kq * 4 + r;
      ile[rt][r] = 1.0f / (lred[rl] + lred[64 + rl]);
    }
    const int rl2 = rh * 32 + rt * 16 + lcol;
    il2[rt] = 1.0f / (lred[rl2] + lred[64 + rl2]);
  }

  // ---- sweep 2 (own K-half): recompute, float4 attn stores ----
  for (int j0 = jbase; j0 < jbase + KHALF; j0 += 64) {
#pragma unroll
    for (int jt = 0; jt < 4; ++jt) {
      const f16* Krow = &K[(size_t)(j0 + jt * 16 + lcol) * DK + kq * 8];
      const f16x8 bk0 = *reinterpret_cast<const f16x8*>(Krow);
      const f16x8 bk1 = *reinterpret_cast<const f16x8*>(Krow + 32);
      const int4 m4 =
          *reinterpret_cast<const int4*>(&msk[j0 + jt * 16 + kq * 4]);
#pragma unroll
      for (int rt = 0; rt < 2; ++rt) {
        f32x4 c = zero;
        c = mfma16(bk0, aq[rt][0], c);
        c = mfma16(bk1, aq[rt][1], c);
        float4 st;
        st.x = m4.x ? __expf(c[0]) * il2[rt] : 0.f;
        st.y = m4.y ? __expf(c[1]) * il2[rt] : 0.f;
        st.z = m4.z ? __expf(c[2]) * il2[rt] : 0.f;
        st.w = m4.w ? __expf(c[3]) * il2[rt] : 0.f;
        *reinterpret_cast<float4*>(
            &Sc[((size_t)(rbase + rt * 16 + lcol) << 11) + j0 + jt * 16 +
                kq * 4]) = st;
      }
    }
  }

  // ---- epilogue: combine O halves, normalize, write ctx (khf==0) ----
  if (khf == 0) {
#pragma unroll
    for (int rt = 0; rt < 2; ++rt)
#pragma unroll
      for (int d = 0; d < 4; ++d) {
        const int dk = d * 16 + lcol;
#pragma unroll
        for (int r = 0; r < 4; ++r) {
          const int rl = rh * 32 + rt * 16 + kq * 4 + r;
          const float ov = o[rt][d][r] + Ost[rl][dk];
          const int s = rbase + rt * 16 + kq * 4 + r;
          ctx[(size_t)(b * S_LEN + s) * DMODEL + h * DK + dk] =
              (f16)(ov * ile[rt][r]);
        }
      }
  }
}

extern "C" void kernel_launch(void* const* d_in, const int* in_sizes, int n_in,
                              void* d_out, int out_size, void* d_ws, size_t ws_size,
                              hipStream_t stream) {
  const float* q = (const float*)d_in[0];
  const float* k = (const float*)d_in[1];
  const float* v = (const float*)d_in[2];
  const int* mask = (const int*)d_in[3];
  const float* w_q = (const float*)d_in[4];
  const float* b_q = (const float*)d_in[5];
  const float* w_v = (const float*)d_in[6];
  const float* b_v = (const float*)d_in[7];
  const float* w_o = (const float*)d_in[8];
  const float* b_o = (const float*)d_in[9];

  float* out = (float*)d_out;
  float* attn = out + (size_t)BS * DMODEL;  // output 1 region

  // workspace (all f16): converted inputs, converted weights, intermediates
  f16* qf = (f16*)d_ws;                      // [BS][DMODEL]
  f16* kf = qf + (size_t)BS * DMODEL;
  f16* vf = kf + (size_t)BS * DMODEL;
  f16* wqf = vf + (size_t)BS * DMODEL;       // [DMODEL][DMODEL]
  f16* wvf = wqf + (size_t)DMODEL * DMODEL;
  f16* wof = wvf + (size_t)DMODEL * DMODEL;
  f16* qh = wof + (size_t)DMODEL * DMODEL;   // [B][H][S][DK] (pre-scaled 0.125)
  f16* kh = qh + (size_t)BS * DMODEL;        // [B][H][S][DK]
  f16* vhT = kh + (size_t)BS * DMODEL;       // [B][H][DK][S]
  f16* ctx = vhT + (size_t)BS * DMODEL;      // [BS][DMODEL]

  cvt6<<<dim3(4096, 6), 256, 0, stream>>>(q, k, v, w_q, w_v, w_o, qf, kf, vf,
                                          wqf, wvf, wof);
  qkv_gemm<<<dim3(8, 32, 3), 256, 0, stream>>>(qf, kf, vf, wqf, b_q, wvf, b_v,
                                               qh, kh, vhT);
  attn_fused<<<dim3(32, 32), 256, 0, stream>>>(qh, kh, vhT, mask, attn, ctx);
  gemm_out<<<dim3(8, 32), 256, 0, stream>>>(ctx, wof, b_o, out);
}

// Round 7
// 919.402 us; speedup vs baseline: 1.1253x; 1.1253x over previous
//
#include <hip/hip_runtime.h>

#define S_LEN 2048
#define DMODEL 1024
#define NH 16
#define DK 64
#define BATCH 2
#define BS (BATCH * S_LEN)  // 4096
#define KHALF 1024

typedef _Float16 f16;
typedef _Float16 f16x8 __attribute__((ext_vector_type(8)));
typedef _Float16 f16x4 __attribute__((ext_vector_type(4)));
typedef float f32x4 __attribute__((ext_vector_type(4)));

__device__ __forceinline__ f32x4 mfma16(f16x8 a, f16x8 b, f32x4 c) {
  return __builtin_amdgcn_mfma_f32_16x16x32_f16(a, b, c, 0, 0, 0);
}

// ---------------------------------------------------------------------------
// Pre-convert fp32 -> f16 for all GEMM operands (activations + weights).
// ---------------------------------------------------------------------------
__global__ __launch_bounds__(256) void cvt6(
    const float* __restrict__ a0, const float* __restrict__ a1,
    const float* __restrict__ a2, const float* __restrict__ a3,
    const float* __restrict__ a4, const float* __restrict__ a5,
    f16* __restrict__ d0, f16* __restrict__ d1, f16* __restrict__ d2,
    f16* __restrict__ d3, f16* __restrict__ d4, f16* __restrict__ d5) {
  const int y = blockIdx.y;
  const float* s;
  f16* d;
  switch (y) {
    case 0: s = a0; d = d0; break;
    case 1: s = a1; d = d1; break;
    case 2: s = a2; d = d2; break;
    case 3: s = a3; d = d3; break;
    case 4: s = a4; d = d4; break;
    default: s = a5; d = d5; break;
  }
  const int n = (y < 3) ? BS * DMODEL : DMODEL * DMODEL;
  const int idx = (blockIdx.x * 256 + threadIdx.x) * 4;
  if (idx >= n) return;
  const float4 v = *reinterpret_cast<const float4*>(&s[idx]);
  f16x4 h = {(f16)v.x, (f16)v.y, (f16)v.z, (f16)v.w};
  *reinterpret_cast<f16x4*>(&d[idx]) = h;
}

// ---------------------------------------------------------------------------
// All-f16 NT GEMM, BK=64.
// MODE 0: f16 head-split [B][H][S][DK]; MODE 1: f16 [B][H][DK][S];
// MODE 2: fp32 row-major.
// ---------------------------------------------------------------------------
template <int MODE>
__device__ __forceinline__ void gemm_body16(const f16* __restrict__ A,
                                            const f16* __restrict__ W,
                                            const float* __restrict__ bias,
                                            void* __restrict__ outp, float scale,
                                            f16 (*As)[72], f16 (*Ws)[72]) {
  const int t = threadIdx.x;
  const int m0 = blockIdx.y * 128;
  const int n0 = blockIdx.x * 128;
  const int wave = t >> 6, lane = t & 63;
  const int wr = wave >> 1, wc = wave & 1;
  const int lcol = lane & 15, kq = lane >> 4;

  f32x4 acc[4][4];
  const f32x4 zero = {0.f, 0.f, 0.f, 0.f};
#pragma unroll
  for (int i = 0; i < 4; ++i)
#pragma unroll
    for (int j = 0; j < 4; ++j) acc[i][j] = zero;

  for (int k0 = 0; k0 < DMODEL; k0 += 64) {
#pragma unroll
    for (int i = 0; i < 4; ++i) {
      const int f = t + i * 256;
      const int r = f >> 3, c = (f & 7) << 3;
      *reinterpret_cast<f16x8*>(&As[r][c]) =
          *reinterpret_cast<const f16x8*>(&A[(size_t)(m0 + r) * DMODEL + k0 + c]);
      *reinterpret_cast<f16x8*>(&Ws[r][c]) =
          *reinterpret_cast<const f16x8*>(&W[(size_t)(n0 + r) * DMODEL + k0 + c]);
    }
    __syncthreads();
#pragma unroll
    for (int ks = 0; ks < 2; ++ks) {
      f16x8 af[4], bf[4];
#pragma unroll
      for (int fr = 0; fr < 4; ++fr)
        af[fr] = *reinterpret_cast<const f16x8*>(
            &As[wr * 64 + fr * 16 + lcol][ks * 32 + kq * 8]);
#pragma unroll
      for (int fc = 0; fc < 4; ++fc)
        bf[fc] = *reinterpret_cast<const f16x8*>(
            &Ws[wc * 64 + fc * 16 + lcol][ks * 32 + kq * 8]);
#pragma unroll
      for (int fr = 0; fr < 4; ++fr)
#pragma unroll
        for (int fc = 0; fc < 4; ++fc)
          acc[fr][fc] = mfma16(af[fr], bf[fc], acc[fr][fc]);
    }
    __syncthreads();
  }

#pragma unroll
  for (int fc = 0; fc < 4; ++fc) {
    const int gj = n0 + wc * 64 + fc * 16 + lcol;
    const float bv = bias[gj];
#pragma unroll
    for (int fr = 0; fr < 4; ++fr) {
#pragma unroll
      for (int r = 0; r < 4; ++r) {
        const int gi = m0 + wr * 64 + fr * 16 + kq * 4 + r;
        const float val = (acc[fr][fc][r] + bv) * scale;
        if constexpr (MODE == 0) {
          const int b = gi >> 11, s = gi & 2047, h = gj >> 6, dk = gj & 63;
          ((f16*)outp)[(((size_t)(b * NH + h) * S_LEN) + s) * DK + dk] = (f16)val;
        } else if constexpr (MODE == 1) {
          const int b = gi >> 11, s = gi & 2047, h = gj >> 6, dk = gj & 63;
          ((f16*)outp)[(((size_t)(b * NH + h) * DK) + dk) * S_LEN + s] = (f16)val;
        } else {
          ((float*)outp)[(size_t)gi * DMODEL + gj] = val;
        }
      }
    }
  }
}

// Fused q/k/v projections (z selects). q output pre-scaled by 1/sqrt(DK).
__global__ __launch_bounds__(256, 3) void qkv_gemm(
    const f16* __restrict__ qf, const f16* __restrict__ kf,
    const f16* __restrict__ vf, const f16* __restrict__ wq,
    const float* __restrict__ b_q, const f16* __restrict__ wv,
    const float* __restrict__ b_v, f16* __restrict__ qh, f16* __restrict__ kh,
    f16* __restrict__ vhT) {
  __shared__ f16 As[128][72];
  __shared__ f16 Ws[128][72];
  if (blockIdx.z == 0)
    gemm_body16<0>(qf, wq, b_q, qh, 0.125f, As, Ws);
  else if (blockIdx.z == 1)
    gemm_body16<0>(kf, wq, b_q, kh, 1.0f, As, Ws);
  else
    gemm_body16<1>(vf, wv, b_v, vhT, 1.0f, As, Ws);
}

__global__ __launch_bounds__(256, 2) void gemm_out(const f16* __restrict__ A,
                                                   const f16* __restrict__ W,
                                                   const float* __restrict__ bias,
                                                   float* __restrict__ outp) {
  __shared__ f16 As[128][72];
  __shared__ f16 Ws[128][72];
  gemm_body16<2>(A, W, bias, outp, 1.0f, As, Ws);
}

// ---------------------------------------------------------------------------
// Fused attention: swapped-operand QK^T (zero-shuffle P/PV, verified R6) +
// block-cooperative COALESCED LDS staging of K/V tiles (fix for R6's
// VMEM-request-rate bound: 16-segment scattered loads -> 8x128B coalesced).
//   block = 4 waves over 64 Q-rows; wave = (row-half rh, K-half khf).
//   Per 64-col round: all 256 threads stage Kt[2]/Vt[2] (32KB, 8 f16x8 loads
//   each, fully coalesced); each wave consumes its half's tiles via ds_read.
// Sweep 1: l_partial + unnormalized O_partial (softmax identity O = O_un/l).
// Combine: Ost/lred overlay the dead V tiles (LDS stays 36.9KB, 4 blk/CU).
// Sweep 2: restage K only, recompute s bit-identically, write attn fp32.
// All arithmetic bit-identical to R6 (absmax unchanged).
// ---------------------------------------------------------------------------
__global__ __launch_bounds__(256, 4) void attn_fused(
    const f16* __restrict__ qh, const f16* __restrict__ kh,
    const f16* __restrict__ vhT, const int* __restrict__ mask,
    float* __restrict__ attn, f16* __restrict__ ctx) {
  // [0, 18432): Kt [2][64][72] f16
  // [18432, 36864): Vt [2][64][72] f16   (sweep 1 only)
  //   overlay after sweep 1: Ost f32 [64][68] (17408) + lred f32 [2][64] (512)
  __shared__ __align__(16) unsigned char smem[36864];
  f16 (*Kt)[64][72] = reinterpret_cast<f16(*)[64][72]>(smem);
  f16 (*Vt)[64][72] = reinterpret_cast<f16(*)[64][72]>(smem + 18432);
  float (*Ost)[68] = reinterpret_cast<float(*)[68]>(smem + 18432);
  float* lred = reinterpret_cast<float*>(smem + 18432 + 17408);

  const int t = threadIdx.x;
  const int bh = blockIdx.y, b = bh >> 4, h = bh & 15;
  const int i0 = blockIdx.x * 64;
  const int wave = t >> 6, lane = t & 63;
  const int rh = wave & 1, khf = wave >> 1;
  const int lcol = lane & 15, kq = lane >> 4;
  const int rbase = i0 + rh * 32;
  const int jbase = khf * KHALF;

  const f16* Q = qh + (size_t)bh * S_LEN * DK;
  const f16* K = kh + (size_t)bh * S_LEN * DK;
  const f16* V = vhT + (size_t)bh * DK * S_LEN;
  const int* msk = mask + b * S_LEN;
  float* Sc = attn + (size_t)bh * S_LEN * S_LEN;

  // Q fragments (B-operand of swapped QK)
  f16x8 aq[2][2];
#pragma unroll
  for (int rt = 0; rt < 2; ++rt)
#pragma unroll
    for (int ks = 0; ks < 2; ++ks)
      aq[rt][ks] = *reinterpret_cast<const f16x8*>(
          &Q[(size_t)(rbase + rt * 16 + lcol) * DK + ks * 32 + kq * 8]);

  float l_acc[2] = {0.f, 0.f};
  f32x4 o[2][4];
  const f32x4 zero = {0.f, 0.f, 0.f, 0.f};
#pragma unroll
  for (int rt = 0; rt < 2; ++rt)
#pragma unroll
    for (int d = 0; d < 4; ++d) o[rt][d] = zero;

  // ---- sweep 1: l_partial + unnormalized PV ----
  for (int j0 = 0; j0 < KHALF; j0 += 64) {
    __syncthreads();  // previous round's tiles fully consumed
    // cooperative coalesced staging: K and V, both halves, cols [j0, j0+64)
#pragma unroll
    for (int hf = 0; hf < 2; ++hf)
#pragma unroll
      for (int i = 0; i < 2; ++i) {
        const int ch = t + i * 256;
        const int r = ch >> 3, c = (ch & 7) << 3;
        *reinterpret_cast<f16x8*>(&Kt[hf][r][c]) =
            *reinterpret_cast<const f16x8*>(
                &K[(size_t)(hf * KHALF + j0 + r) * DK + c]);
        *reinterpret_cast<f16x8*>(&Vt[hf][r][c]) =
            *reinterpret_cast<const f16x8*>(
                &V[(size_t)r * S_LEN + hf * KHALF + j0 + c]);
      }
    __syncthreads();  // tiles ready
#pragma unroll
    for (int jh = 0; jh < 2; ++jh) {  // 32-k chunk
      f16x8 ap[2];
#pragma unroll
      for (int jl = 0; jl < 2; ++jl) {
        const int jt = jh * 2 + jl;
        const f16x8 bk0 =
            *reinterpret_cast<const f16x8*>(&Kt[khf][jt * 16 + lcol][kq * 8]);
        const f16x8 bk1 = *reinterpret_cast<const f16x8*>(
            &Kt[khf][jt * 16 + lcol][kq * 8 + 32]);
        const int4 m4 = *reinterpret_cast<const int4*>(
            &msk[jbase + j0 + jt * 16 + kq * 4]);
#pragma unroll
        for (int rt = 0; rt < 2; ++rt) {
          f32x4 c = zero;
          c = mfma16(bk0, aq[rt][0], c);
          c = mfma16(bk1, aq[rt][1], c);
          const float p0 = m4.x ? __expf(c[0]) : 0.f;
          const float p1 = m4.y ? __expf(c[1]) : 0.f;
          const float p2 = m4.z ? __expf(c[2]) : 0.f;
          const float p3 = m4.w ? __expf(c[3]) : 0.f;
          l_acc[rt] += (p0 + p1) + (p2 + p3);
          ap[rt][jl * 4 + 0] = (f16)p0;
          ap[rt][jl * 4 + 1] = (f16)p1;
          ap[rt][jl * 4 + 2] = (f16)p2;
          ap[rt][jl * 4 + 3] = (f16)p3;
        }
      }
      // PV: V fragment from LDS under the same k-permutation (lane-local k)
#pragma unroll
      for (int d = 0; d < 4; ++d) {
        const f16* Vr = &Vt[khf][d * 16 + lcol][jh * 32 + kq * 4];
        const f16x4 v0 = *reinterpret_cast<const f16x4*>(Vr);
        const f16x4 v1 = *reinterpret_cast<const f16x4*>(Vr + 16);
        f16x8 bv;
        bv[0] = v0[0]; bv[1] = v0[1]; bv[2] = v0[2]; bv[3] = v0[3];
        bv[4] = v1[0]; bv[5] = v1[1]; bv[6] = v1[2]; bv[7] = v1[3];
#pragma unroll
        for (int rt = 0; rt < 2; ++rt) o[rt][d] = mfma16(ap[rt], bv, o[rt][d]);
      }
    }
  }

  // ---- reduce l over the 4 kq lane-groups (k-axis) ----
#pragma unroll
  for (int rt = 0; rt < 2; ++rt) {
    float es = l_acc[rt];
    es += __shfl_xor(es, 16);
    es += __shfl_xor(es, 32);
    l_acc[rt] = es;
  }

  // ---- cross-wave combine (Ost/lred overlay the dead V tiles) ----
  __syncthreads();  // all waves done reading Vt
  if (kq == 0) {
#pragma unroll
    for (int rt = 0; rt < 2; ++rt)
      lred[khf * 64 + rh * 32 + rt * 16 + lcol] = l_acc[rt];
  }
  if (khf == 1) {
#pragma unroll
    for (int rt = 0; rt < 2; ++rt)
#pragma unroll
      for (int d = 0; d < 4; ++d)
#pragma unroll
        for (int r = 0; r < 4; ++r)
          Ost[rh * 32 + rt * 16 + kq * 4 + r][d * 16 + lcol] = o[rt][d][r];
  }
  __syncthreads();

  float ile[2][4];  // q = kq*4+r layout (epilogue)
  float il2[2];     // q = lcol layout (sweep 2 stores)
#pragma unroll
  for (int rt = 0; rt < 2; ++rt) {
#pragma unroll
    for (int r = 0; r < 4; ++r) {
      const int rl = rh * 32 + rt * 16 + kq * 4 + r;
      ile[rt][r] = 1.0f / (lred[rl] + lred[64 + rl]);
    }
    const int rl2 = rh * 32 + rt * 16 + lcol;
    il2[rt] = 1.0f / (lred[rl2] + lred[64 + rl2]);
  }

  // ---- sweep 2: restage K only, recompute, float4 attn stores ----
  for (int j0 = 0; j0 < KHALF; j0 += 64) {
    __syncthreads();  // previous Kt consumed (Ost region untouched)
#pragma unroll
    for (int hf = 0; hf < 2; ++hf)
#pragma unroll
      for (int i = 0; i < 2; ++i) {
        const int ch = t + i * 256;
        const int r = ch >> 3, c = (ch & 7) << 3;
        *reinterpret_cast<f16x8*>(&Kt[hf][r][c]) =
            *reinterpret_cast<const f16x8*>(
                &K[(size_t)(hf * KHALF + j0 + r) * DK + c]);
      }
    __syncthreads();
#pragma unroll
    for (int jt = 0; jt < 4; ++jt) {
      const f16x8 bk0 =
          *reinterpret_cast<const f16x8*>(&Kt[khf][jt * 16 + lcol][kq * 8]);
      const f16x8 bk1 = *reinterpret_cast<const f16x8*>(
          &Kt[khf][jt * 16 + lcol][kq * 8 + 32]);
      const int4 m4 =
          *reinterpret_cast<const int4*>(&msk[jbase + j0 + jt * 16 + kq * 4]);
#pragma unroll
      for (int rt = 0; rt < 2; ++rt) {
        f32x4 c = zero;
        c = mfma16(bk0, aq[rt][0], c);
        c = mfma16(bk1, aq[rt][1], c);
        float4 st;
        st.x = m4.x ? __expf(c[0]) * il2[rt] : 0.f;
        st.y = m4.y ? __expf(c[1]) * il2[rt] : 0.f;
        st.z = m4.z ? __expf(c[2]) * il2[rt] : 0.f;
        st.w = m4.w ? __expf(c[3]) * il2[rt] : 0.f;
        *reinterpret_cast<float4*>(
            &Sc[((size_t)(rbase + rt * 16 + lcol) << 11) + jbase + j0 +
                jt * 16 + kq * 4]) = st;
      }
    }
  }

  // ---- epilogue: combine O halves, normalize, write ctx (khf==0) ----
  if (khf == 0) {
#pragma unroll
    for (int rt = 0; rt < 2; ++rt)
#pragma unroll
      for (int d = 0; d < 4; ++d) {
        const int dk = d * 16 + lcol;
#pragma unroll
        for (int r = 0; r < 4; ++r) {
          const int rl = rh * 32 + rt * 16 + kq * 4 + r;
          const float ov = o[rt][d][r] + Ost[rl][dk];
          const int s = rbase + rt * 16 + kq * 4 + r;
          ctx[(size_t)(b * S_LEN + s) * DMODEL + h * DK + dk] =
              (f16)(ov * ile[rt][r]);
        }
      }
  }
}

extern "C" void kernel_launch(void* const* d_in, const int* in_sizes, int n_in,
                              void* d_out, int out_size, void* d_ws, size_t ws_size,
                              hipStream_t stream) {
  const float* q = (const float*)d_in[0];
  const float* k = (const float*)d_in[1];
  const float* v = (const float*)d_in[2];
  const int* mask = (const int*)d_in[3];
  const float* w_q = (const float*)d_in[4];
  const float* b_q = (const float*)d_in[5];
  const float* w_v = (const float*)d_in[6];
  const float* b_v = (const float*)d_in[7];
  const float* w_o = (const float*)d_in[8];
  const float* b_o = (const float*)d_in[9];

  float* out = (float*)d_out;
  float* attn = out + (size_t)BS * DMODEL;  // output 1 region

  // workspace (all f16): converted inputs, converted weights, intermediates
  f16* qf = (f16*)d_ws;                      // [BS][DMODEL]
  f16* kf = qf + (size_t)BS * DMODEL;
  f16* vf = kf + (size_t)BS * DMODEL;
  f16* wqf = vf + (size_t)BS * DMODEL;       // [DMODEL][DMODEL]
  f16* wvf = wqf + (size_t)DMODEL * DMODEL;
  f16* wof = wvf + (size_t)DMODEL * DMODEL;
  f16* qh = wof + (size_t)DMODEL * DMODEL;   // [B][H][S][DK] (pre-scaled 0.125)
  f16* kh = qh + (size_t)BS * DMODEL;        // [B][H][S][DK]
  f16* vhT = kh + (size_t)BS * DMODEL;       // [B][H][DK][S]
  f16* ctx = vhT + (size_t)BS * DMODEL;      // [BS][DMODEL]

  cvt6<<<dim3(4096, 6), 256, 0, stream>>>(q, k, v, w_q, w_v, w_o, qf, kf, vf,
                                          wqf, wvf, wof);
  qkv_gemm<<<dim3(8, 32, 3), 256, 0, stream>>>(qf, kf, vf, wqf, b_q, wvf, b_v,
                                               qh, kh, vhT);
  attn_fused<<<dim3(32, 32), 256, 0, stream>>>(qh, kh, vhT, mask, attn, ctx);
  gemm_out<<<dim3(8, 32), 256, 0, stream>>>(ctx, wof, b_o, out);
}